// Round 8
// baseline (237.730 us; speedup 1.0000x reference)
//
#include <hip/hip_runtime.h>
#include <hip/hip_bf16.h>

#define DD 256
#define CC 104
#define FT_STRIDE 264   // bf16 units; 528B LDS rows (16B-aligned)

typedef __bf16 bf16x8 __attribute__((ext_vector_type(8)));
typedef float  f32x4  __attribute__((ext_vector_type(4)));

__device__ inline float bu2f(unsigned short u) {
    return __uint_as_float(((unsigned)u) << 16);
}
__device__ inline unsigned short f2bu(float f) {
    __hip_bfloat16 h = __float2bfloat16(f);
    return *reinterpret_cast<unsigned short*>(&h);
}

// ---------------------------------------------------------------------------
// Kernel 1: ALL prep in one launch, block-range partitioned:
//  [0,PB)          per-edge: segment boundaries + edge_tok gather
//  [PB,PB+32)      W  -> bf16 MFMA-fragment order (128 groups of 1KB)
//  [PB+32,PB+48)   Wc -> bf16 fragment order, zero-padded to 128 rows
//  [PB+48,...)     emb -> bf16 (float4 -> ushort4 streaming)
// Fragment layout: group g, lane s, elems j<8:
//   frag[g*512 + s*8 + j] = Wsrc[(nt*16 + (s&15))*256 + k0*32 + (s>>4)*8 + j]
//   rnn: g = k0*16 + nt (8 k0 x 16 nt);  cls: g = k0*8 + nt (8 k0 x 8 nt)
// ---------------------------------------------------------------------------
__global__ void prep_all(
    const int* __restrict__ token_id,
    const int* __restrict__ src_idx,
    const int* __restrict__ dst_idx,
    int* __restrict__ seg_start,
    int* __restrict__ seg_end,
    int* __restrict__ edge_tok,
    int E, int PB,
    const float* __restrict__ W,
    const float* __restrict__ Wc,
    __hip_bfloat16* __restrict__ Wfrag,
    __hip_bfloat16* __restrict__ Wcfrag,
    const float* __restrict__ emb,
    __hip_bfloat16* __restrict__ embb,
    int nE4)
{
    const int b = blockIdx.x;
    const int t = threadIdx.x;
    if (b < PB) {
        int e = b * 256 + t;
        if (e >= E) return;
        int d = dst_idx[e];
        edge_tok[e] = token_id[src_idx[e]];
        if (e == 0 || dst_idx[e - 1] != d) seg_start[d] = e;
        if (e == E - 1 || dst_idx[e + 1] != d) seg_end[d] = e + 1;
        return;
    }
    if (b < PB + 32) {                      // W fragment reorder
        int idx  = (b - PB) * 256 + t;      // 0..8191
        int lane = idx & 63, g = idx >> 6;  // g = k0*16 + nt
        int nt = g & 15, k0 = g >> 4;
        int r = nt * 16 + (lane & 15);
        int c = k0 * 32 + (lane >> 4) * 8;
        const float* src = W + (size_t)r * DD + c;
        float4 v0 = *(const float4*)(src);
        float4 v1 = *(const float4*)(src + 4);
        uint4 pk;
        pk.x = (unsigned)f2bu(v0.x) | ((unsigned)f2bu(v0.y) << 16);
        pk.y = (unsigned)f2bu(v0.z) | ((unsigned)f2bu(v0.w) << 16);
        pk.z = (unsigned)f2bu(v1.x) | ((unsigned)f2bu(v1.y) << 16);
        pk.w = (unsigned)f2bu(v1.z) | ((unsigned)f2bu(v1.w) << 16);
        *(uint4*)(Wfrag + (size_t)idx * 8) = pk;
        return;
    }
    if (b < PB + 48) {                      // Wc fragment reorder (padded)
        int idx  = (b - PB - 32) * 256 + t; // 0..4095
        int lane = idx & 63, g = idx >> 6;  // g = k0*8 + nt
        int nt = g & 7, k0 = g >> 3;
        int r = nt * 16 + (lane & 15);      // 0..127
        int c = k0 * 32 + (lane >> 4) * 8;
        float4 v0 = make_float4(0.f,0.f,0.f,0.f);
        float4 v1 = make_float4(0.f,0.f,0.f,0.f);
        if (r < CC) {
            const float* src = Wc + (size_t)r * DD + c;
            v0 = *(const float4*)(src);
            v1 = *(const float4*)(src + 4);
        }
        uint4 pk;
        pk.x = (unsigned)f2bu(v0.x) | ((unsigned)f2bu(v0.y) << 16);
        pk.y = (unsigned)f2bu(v0.z) | ((unsigned)f2bu(v0.w) << 16);
        pk.z = (unsigned)f2bu(v1.x) | ((unsigned)f2bu(v1.y) << 16);
        pk.w = (unsigned)f2bu(v1.z) | ((unsigned)f2bu(v1.w) << 16);
        *(uint4*)(Wcfrag + (size_t)idx * 8) = pk;
        return;
    }
    int i = (b - PB - 48) * 256 + t;        // emb convert
    if (i >= nE4) return;
    float4 v = ((const float4*)emb)[i];
    ushort4 o;
    o.x = f2bu(v.x); o.y = f2bu(v.y); o.z = f2bu(v.z); o.w = f2bu(v.w);
    *(ushort4*)(embb + (size_t)i * 4) = o;
}

// ---------------------------------------------------------------------------
// Kernel 2: MEGA — seg_sum + rnn + cls fused, NO __syncthreads.
// Block = 4 waves x 16 rows; each wave fully independent (wave-private LDS).
//  A: per dst (wave-per-dst, half-wave-per-edge, 16B lanes): child sum ->
//     LDS child tile (bf16). Seg metadata prefetched lane-parallel + __shfl.
//  B: rnn MFMAs, swapped operands (A=W-frag from L2 frag-ordered buffer,
//     B=child frag from LDS). D: row = l16, cols nt*16+quad*4+r.
//  C: relu+bias -> transpose through LDS tile -> + last_msg row-frags ->
//     ft frags in registers.
//  D: cls MFMAs (Wc-frags from L2) -> out (float4 stores).
// ---------------------------------------------------------------------------
__global__ __launch_bounds__(256, 3) void mega(
    const __hip_bfloat16* __restrict__ embb,   // [V,256] bf16
    const int* __restrict__ edge_tok,
    const int* __restrict__ seg_start,
    const int* __restrict__ seg_end,
    const __hip_bfloat16* __restrict__ Wfrag,  // frag-ordered W
    const float* __restrict__ bvec,            // [256]
    const __hip_bfloat16* __restrict__ Wcfrag, // frag-ordered Wc (padded)
    const float* __restrict__ bc,              // [104]
    float* __restrict__ out,                   // [M,104]
    int M)
{
    extern __shared__ char smem[];
    __hip_bfloat16* child = (__hip_bfloat16*)smem;   // [64][FT_STRIDE]
    const int t    = threadIdx.x;
    const int lane = t & 63;
    const int w    = t >> 6;
    const int quad = lane >> 4;
    const int l16  = lane & 15;
    const int h    = lane >> 5;
    const int l32  = lane & 31;
    const int rb   = w * 16;                 // wave's row base in block
    const int mb   = blockIdx.x * 64 + rb;   // wave's first global row

    // --- lane-parallel seg metadata prefetch (row = l16) ---
    int mm0 = min(mb + l16, M - 1);
    int sA  = seg_start[mm0];
    int eA  = seg_end[mm0];
    int ltA = edge_tok[eA - 1];              // last-edge token for row l16
    bool muA = (eA - sA) > 1;

    // ---- phase A: segment sums for the wave's 16 rows ----
    for (int j = 0; j < 16; ++j) {
        int s = __shfl(sA, j, 64);
        int e = __shfl(eA, j, 64) - 1;       // exclude last edge
        float acc[8] = {0.f,0.f,0.f,0.f,0.f,0.f,0.f,0.f};
        int i = s + h;
        for (; i + 6 < e; i += 8) {          // 4 edges per half-wave in flight
            int t0 = edge_tok[i];
            int t1 = edge_tok[i + 2];
            int t2 = edge_tok[i + 4];
            int t3 = edge_tok[i + 6];
            uint4 u0 = *(const uint4*)(embb + (size_t)t0 * DD + l32 * 8);
            uint4 u1 = *(const uint4*)(embb + (size_t)t1 * DD + l32 * 8);
            uint4 u2 = *(const uint4*)(embb + (size_t)t2 * DD + l32 * 8);
            uint4 u3 = *(const uint4*)(embb + (size_t)t3 * DD + l32 * 8);
            const unsigned* a0 = (const unsigned*)&u0;
            const unsigned* a1 = (const unsigned*)&u1;
            const unsigned* a2 = (const unsigned*)&u2;
            const unsigned* a3 = (const unsigned*)&u3;
#pragma unroll
            for (int d = 0; d < 4; ++d) {
                acc[2*d]   += (__uint_as_float(a0[d] << 16) + __uint_as_float(a1[d] << 16))
                            + (__uint_as_float(a2[d] << 16) + __uint_as_float(a3[d] << 16));
                acc[2*d+1] += (__uint_as_float(a0[d] & 0xffff0000u) + __uint_as_float(a1[d] & 0xffff0000u))
                            + (__uint_as_float(a2[d] & 0xffff0000u) + __uint_as_float(a3[d] & 0xffff0000u));
            }
        }
        for (; i < e; i += 2) {
            int t0 = edge_tok[i];
            uint4 u = *(const uint4*)(embb + (size_t)t0 * DD + l32 * 8);
            const unsigned* ud = (const unsigned*)&u;
#pragma unroll
            for (int d = 0; d < 4; ++d) {
                acc[2*d]   += __uint_as_float(ud[d] << 16);
                acc[2*d+1] += __uint_as_float(ud[d] & 0xffff0000u);
            }
        }
#pragma unroll
        for (int jj = 0; jj < 8; ++jj) acc[jj] += __shfl_xor(acc[jj], 32, 64);
        if (h == 0) {
            uint4 o;
            unsigned* od = (unsigned*)&o;
#pragma unroll
            for (int d = 0; d < 4; ++d)
                od[d] = (unsigned)f2bu(acc[2*d]) | ((unsigned)f2bu(acc[2*d+1]) << 16);
            *(uint4*)(child + (rb + j) * FT_STRIDE + l32 * 8) = o;
        }
    }
    // wave-private LDS rows: no barrier needed anywhere in this kernel

    // ---- phase B: rnn GEMM ----
    const __hip_bfloat16* crow = child + (rb + l16) * FT_STRIDE + quad * 8;
    bf16x8 cfrag[8];
#pragma unroll
    for (int k0 = 0; k0 < 8; ++k0)
        cfrag[k0] = *(const bf16x8*)(crow + k0 * 32);

    f32x4 acc1[16];
#pragma unroll
    for (int nt = 0; nt < 16; ++nt) acc1[nt] = (f32x4){0.f,0.f,0.f,0.f};
#pragma unroll
    for (int k0 = 0; k0 < 8; ++k0) {
#pragma unroll
        for (int nt = 0; nt < 16; ++nt) {
            bf16x8 wf = *(const bf16x8*)(Wfrag + ((k0 * 16 + nt) * 512) + lane * 8);
            acc1[nt] = __builtin_amdgcn_mfma_f32_16x16x32_bf16(wf, cfrag[k0], acc1[nt], 0, 0, 0);
        }
    }

    // ---- phase C: relu+bias -> LDS transpose -> + last_msg ----
#pragma unroll
    for (int nt = 0; nt < 16; ++nt) {
        float4 bia = *(const float4*)(bvec + nt * 16 + quad * 4);
        ushort4 o;
        o.x = f2bu(muA ? fmaxf(acc1[nt][0] + bia.x, 0.f) : 0.f);
        o.y = f2bu(muA ? fmaxf(acc1[nt][1] + bia.y, 0.f) : 0.f);
        o.z = f2bu(muA ? fmaxf(acc1[nt][2] + bia.z, 0.f) : 0.f);
        o.w = f2bu(muA ? fmaxf(acc1[nt][3] + bia.w, 0.f) : 0.f);
        *(ushort4*)(child + (rb + l16) * FT_STRIDE + nt * 16 + quad * 4) = o;
    }

    const __hip_bfloat16* lrow = embb + (size_t)ltA * DD + quad * 8;
    bf16x8 ff[8];
#pragma unroll
    for (int k0 = 0; k0 < 8; ++k0) {
        bf16x8 rp = *(const bf16x8*)(crow + k0 * 32);
        bf16x8 lm = *(const bf16x8*)(lrow + k0 * 32);
        bf16x8 o;
#pragma unroll
        for (int j = 0; j < 8; ++j)
            o[j] = (__bf16)((float)rp[j] + (float)lm[j]);
        ff[k0] = o;
    }

    // ---- phase D: cls GEMM ----
    f32x4 acc2[8];
#pragma unroll
    for (int nt = 0; nt < 8; ++nt) acc2[nt] = (f32x4){0.f,0.f,0.f,0.f};
#pragma unroll
    for (int k0 = 0; k0 < 8; ++k0) {
#pragma unroll
        for (int nt = 0; nt < 8; ++nt) {
            bf16x8 wcf = *(const bf16x8*)(Wcfrag + ((k0 * 8 + nt) * 512) + lane * 8);
            acc2[nt] = __builtin_amdgcn_mfma_f32_16x16x32_bf16(wcf, ff[k0], acc2[nt], 0, 0, 0);
        }
    }

    int m = mb + l16;
    if (m < M) {
#pragma unroll
        for (int nt = 0; nt < 8; ++nt) {
            int c0 = nt * 16 + quad * 4;
            if (c0 <= 100) {
                float4 bia = *(const float4*)(bc + c0);
                float4 o;
                o.x = acc2[nt][0] + bia.x;
                o.y = acc2[nt][1] + bia.y;
                o.z = acc2[nt][2] + bia.z;
                o.w = acc2[nt][3] + bia.w;
                *(float4*)(out + (size_t)m * CC + c0) = o;
            }
        }
    }
}

// ---------------------------------------------------------------------------
extern "C" void kernel_launch(void* const* d_in, const int* in_sizes, int n_in,
                              void* d_out, int out_size, void* d_ws, size_t ws_size,
                              hipStream_t stream)
{
    const float* emb      = (const float*)d_in[0];
    const float* W        = (const float*)d_in[1];
    const float* bvec     = (const float*)d_in[2];
    const float* Wc       = (const float*)d_in[3];
    const float* bc       = (const float*)d_in[4];
    const int*   token_id = (const int*)d_in[5];
    const int*   src_idx  = (const int*)d_in[6];
    const int*   dst_idx  = (const int*)d_in[7];
    float*       out      = (float*)d_out;

    const int E     = in_sizes[6];
    const int Vemb  = in_sizes[0] / DD;
    const int n_dst = out_size / CC;
    (void)n_in; (void)ws_size;

    char* ws = (char*)d_ws;
    size_t off = 0;
    auto alloc = [&](size_t bytes) {
        void* p = ws + off;
        off = (off + bytes + 255) & ~(size_t)255;
        return p;
    };
    int* seg_start = (int*)alloc((size_t)n_dst * sizeof(int));
    int* seg_end   = (int*)alloc((size_t)n_dst * sizeof(int));
    int* edge_tok  = (int*)alloc((size_t)E * sizeof(int));
    __hip_bfloat16* embb   = (__hip_bfloat16*)alloc((size_t)Vemb * DD * 2);
    __hip_bfloat16* Wfrag  = (__hip_bfloat16*)alloc((size_t)128 * 512 * 2);
    __hip_bfloat16* Wcfrag = (__hip_bfloat16*)alloc((size_t)64 * 512 * 2);

    const int nE4 = Vemb * (DD / 4);
    const int PB  = (E + 255) / 256;
    const int cvtB = (nE4 + 255) / 256;
    const int mega_blocks = (n_dst + 63) / 64;
    const int lds_bytes = 64 * FT_STRIDE * 2;   // 33792

    prep_all<<<PB + 48 + cvtB, 256, 0, stream>>>(
        token_id, src_idx, dst_idx, seg_start, seg_end, edge_tok, E, PB,
        W, Wc, Wfrag, Wcfrag, emb, embb, nE4);
    mega<<<mega_blocks, 256, lds_bytes, stream>>>(
        embb, edge_tok, seg_start, seg_end, Wfrag, bvec, Wcfrag, bc,
        out, n_dst);
}

// Round 9
// 192.702 us; speedup vs baseline: 1.2337x; 1.2337x over previous
//
#include <hip/hip_runtime.h>
#include <hip/hip_bf16.h>

#define DD 256
#define CC 104

typedef __bf16 bf16x8 __attribute__((ext_vector_type(8)));
typedef float  f32x4  __attribute__((ext_vector_type(4)));

__device__ inline float bu2f(unsigned short u) {
    return __uint_as_float(((unsigned)u) << 16);
}
__device__ inline unsigned short f2bu(float f) {
    __hip_bfloat16 h = __float2bfloat16(f);
    return *reinterpret_cast<unsigned short*>(&h);
}

// ---------------------------------------------------------------------------
// Kernel 1: prep — per-edge boundaries/tokens + W,Wc -> bf16 fragment order.
// Fragment layout (g = group, s = lane, j<8):
//   frag[g*512 + s*8 + j] = Wsrc[(nt*16 + (s&15))*256 + k0*32 + (s>>4)*8 + j]
//   W: g = k0*16 + nt (8 x 16);  Wc: g = k0*8 + nt (8 x 8, rows padded to 128)
// ---------------------------------------------------------------------------
__global__ void prep_all(
    const int* __restrict__ token_id,
    const int* __restrict__ src_idx,
    const int* __restrict__ dst_idx,
    int* __restrict__ seg_start,
    int* __restrict__ seg_end,
    int* __restrict__ edge_tok,
    int E, int PB,
    const float* __restrict__ W,
    const float* __restrict__ Wc,
    __hip_bfloat16* __restrict__ Wfrag,
    __hip_bfloat16* __restrict__ Wcfrag)
{
    const int b = blockIdx.x;
    const int t = threadIdx.x;
    if (b < PB) {
        int e = b * 256 + t;
        if (e >= E) return;
        int d = dst_idx[e];
        edge_tok[e] = token_id[src_idx[e]];
        if (e == 0 || dst_idx[e - 1] != d) seg_start[d] = e;
        if (e == E - 1 || dst_idx[e + 1] != d) seg_end[d] = e + 1;
        return;
    }
    if (b < PB + 32) {                      // W fragment reorder
        int idx  = (b - PB) * 256 + t;      // 0..8191
        int lane = idx & 63, g = idx >> 6;  // g = k0*16 + nt
        int nt = g & 15, k0 = g >> 4;
        int r = nt * 16 + (lane & 15);
        int c = k0 * 32 + (lane >> 4) * 8;
        const float* src = W + (size_t)r * DD + c;
        float4 v0 = *(const float4*)(src);
        float4 v1 = *(const float4*)(src + 4);
        uint4 pk;
        pk.x = (unsigned)f2bu(v0.x) | ((unsigned)f2bu(v0.y) << 16);
        pk.y = (unsigned)f2bu(v0.z) | ((unsigned)f2bu(v0.w) << 16);
        pk.z = (unsigned)f2bu(v1.x) | ((unsigned)f2bu(v1.y) << 16);
        pk.w = (unsigned)f2bu(v1.z) | ((unsigned)f2bu(v1.w) << 16);
        *(uint4*)(Wfrag + (size_t)idx * 8) = pk;
        return;
    }
    {                                       // Wc fragment reorder (padded)
        int idx  = (b - PB - 32) * 256 + t; // 0..4095
        int lane = idx & 63, g = idx >> 6;  // g = k0*8 + nt
        int nt = g & 7, k0 = g >> 3;
        int r = nt * 16 + (lane & 15);      // 0..127
        int c = k0 * 32 + (lane >> 4) * 8;
        float4 v0 = make_float4(0.f,0.f,0.f,0.f);
        float4 v1 = make_float4(0.f,0.f,0.f,0.f);
        if (r < CC) {
            const float* src = Wc + (size_t)r * DD + c;
            v0 = *(const float4*)(src);
            v1 = *(const float4*)(src + 4);
        }
        uint4 pk;
        pk.x = (unsigned)f2bu(v0.x) | ((unsigned)f2bu(v0.y) << 16);
        pk.y = (unsigned)f2bu(v0.z) | ((unsigned)f2bu(v0.w) << 16);
        pk.z = (unsigned)f2bu(v1.x) | ((unsigned)f2bu(v1.y) << 16);
        pk.w = (unsigned)f2bu(v1.z) | ((unsigned)f2bu(v1.w) << 16);
        *(uint4*)(Wcfrag + (size_t)idx * 8) = pk;
    }
}

// ---------------------------------------------------------------------------
// Kernel 2: We = emb @ W^T for ALL tokens (dense streaming MFMA GEMM).
// Also emits embb (bf16 emb) as a side product of the rows it streams.
// Block = 4 waves x 16 rows = 64 token rows; W staged in 4 x 32KB phases
// (straight copy of frag-ordered Wfrag). Swapped operands:
//   mfma(A=W-frag, B=emb-frag) -> lane's D = We[row=vb+l16][nt*16+quad*4+r]
// ---------------------------------------------------------------------------
__global__ __launch_bounds__(256, 3) void we_gemm(
    const float* __restrict__ emb,             // [V,256] fp32
    const __hip_bfloat16* __restrict__ Wfrag,  // 128 groups x 512
    __hip_bfloat16* __restrict__ Webuf,        // [V,256] bf16 out
    __hip_bfloat16* __restrict__ embb,         // [V,256] bf16 out
    int V)
{
    __shared__ __hip_bfloat16 lds[32 * 512];   // 32KB
    const int t    = threadIdx.x;
    const int lane = t & 63;
    const int w    = t >> 6;
    const int quad = lane >> 4;
    const int l16  = lane & 15;
    const int mrow = blockIdx.x * 64 + w * 16 + l16;
    const int row  = min(mrow, V - 1);

    // stream emb row fp32 -> bf16 frags (+ embb side-write)
    bf16x8 bfrag[8];
#pragma unroll
    for (int k0 = 0; k0 < 8; ++k0) {
        const float* src = emb + (size_t)row * DD + k0 * 32 + quad * 8;
        float4 v0 = *(const float4*)(src);
        float4 v1 = *(const float4*)(src + 4);
        uint4 pk;
        pk.x = (unsigned)f2bu(v0.x) | ((unsigned)f2bu(v0.y) << 16);
        pk.y = (unsigned)f2bu(v0.z) | ((unsigned)f2bu(v0.w) << 16);
        pk.z = (unsigned)f2bu(v1.x) | ((unsigned)f2bu(v1.y) << 16);
        pk.w = (unsigned)f2bu(v1.z) | ((unsigned)f2bu(v1.w) << 16);
        bfrag[k0] = *(bf16x8*)&pk;
        if (mrow < V)
            *(uint4*)(embb + (size_t)row * DD + k0 * 32 + quad * 8) = pk;
    }

    f32x4 acc[16];
#pragma unroll
    for (int nt = 0; nt < 16; ++nt) acc[nt] = (f32x4){0.f,0.f,0.f,0.f};

    for (int p = 0; p < 4; ++p) {
        if (p) __syncthreads();
        // straight-copy groups [32p, 32p+32): 32KB
#pragma unroll
        for (int it = 0; it < 8; ++it) {
            int idx = it * 256 + t;
            *(uint4*)(lds + (size_t)idx * 8) =
                *(const uint4*)(Wfrag + (size_t)p * 16384 + (size_t)idx * 8);
        }
        __syncthreads();
#pragma unroll
        for (int kl = 0; kl < 2; ++kl) {
            int k0 = p * 2 + kl;
#pragma unroll
            for (int nt = 0; nt < 16; ++nt) {
                bf16x8 wf = *(const bf16x8*)(lds + (kl * 16 + nt) * 512 + lane * 8);
                acc[nt] = __builtin_amdgcn_mfma_f32_16x16x32_bf16(wf, bfrag[k0], acc[nt], 0, 0, 0);
            }
        }
    }

    if (mrow < V) {
#pragma unroll
        for (int nt = 0; nt < 16; ++nt) {
            ushort4 o;
            o.x = f2bu(acc[nt][0]);
            o.y = f2bu(acc[nt][1]);
            o.z = f2bu(acc[nt][2]);
            o.w = f2bu(acc[nt][3]);
            *(ushort4*)(Webuf + (size_t)mrow * DD + nt * 16 + quad * 4) = o;
        }
    }
}

// ---------------------------------------------------------------------------
// Kernel 3: segment sum over We rows + FULL rnn epilogue.
// One wave per dst (50k waves -> max gather concurrency, the R8 lesson).
//   r = sum_{edges except last} We[tok]   (bf16 rows, fp32 accumulate)
//   ft = embb[last_tok] + (deg>1 ? relu(r + b) : 0)   -> bf16 ftb
// ---------------------------------------------------------------------------
__global__ void seg_rnn_kernel(const __hip_bfloat16* __restrict__ Webuf,
                               const __hip_bfloat16* __restrict__ embb,
                               const int* __restrict__ edge_tok,
                               const int* __restrict__ seg_start,
                               const int* __restrict__ seg_end,
                               const float* __restrict__ bvec,
                               __hip_bfloat16* __restrict__ ftb,
                               int n_dst)
{
    int w = (blockIdx.x * blockDim.x + threadIdx.x) >> 6;
    int lane = threadIdx.x & 63;
    if (w >= n_dst) return;
    int h   = lane >> 5;
    int l32 = lane & 31;
    int s  = seg_start[w];
    int e  = seg_end[w];
    int lt = edge_tok[e - 1];
    bool gate = (e - s) > 1;
    int e1 = e - 1;                   // exclude last edge
    float acc[8] = {0.f,0.f,0.f,0.f,0.f,0.f,0.f,0.f};

    int i = s + h;
    for (; i + 6 < e1; i += 8) {      // 4 row-gathers in flight per thread
        int t0 = edge_tok[i];
        int t1 = edge_tok[i + 2];
        int t2 = edge_tok[i + 4];
        int t3 = edge_tok[i + 6];
        uint4 u0 = *(const uint4*)(Webuf + (size_t)t0 * DD + l32 * 8);
        uint4 u1 = *(const uint4*)(Webuf + (size_t)t1 * DD + l32 * 8);
        uint4 u2 = *(const uint4*)(Webuf + (size_t)t2 * DD + l32 * 8);
        uint4 u3 = *(const uint4*)(Webuf + (size_t)t3 * DD + l32 * 8);
        const unsigned* a0 = (const unsigned*)&u0;
        const unsigned* a1 = (const unsigned*)&u1;
        const unsigned* a2 = (const unsigned*)&u2;
        const unsigned* a3 = (const unsigned*)&u3;
#pragma unroll
        for (int d = 0; d < 4; ++d) {
            acc[2*d]   += (__uint_as_float(a0[d] << 16) + __uint_as_float(a1[d] << 16))
                        + (__uint_as_float(a2[d] << 16) + __uint_as_float(a3[d] << 16));
            acc[2*d+1] += (__uint_as_float(a0[d] & 0xffff0000u) + __uint_as_float(a1[d] & 0xffff0000u))
                        + (__uint_as_float(a2[d] & 0xffff0000u) + __uint_as_float(a3[d] & 0xffff0000u));
        }
    }
    for (; i < e1; i += 2) {
        int t0 = edge_tok[i];
        uint4 u = *(const uint4*)(Webuf + (size_t)t0 * DD + l32 * 8);
        const unsigned* ud = (const unsigned*)&u;
#pragma unroll
        for (int d = 0; d < 4; ++d) {
            acc[2*d]   += __uint_as_float(ud[d] << 16);
            acc[2*d+1] += __uint_as_float(ud[d] & 0xffff0000u);
        }
    }

#pragma unroll
    for (int j = 0; j < 8; ++j) acc[j] += __shfl_xor(acc[j], 32, 64);

    if (h == 0) {
        float4 b0 = *(const float4*)(bvec + l32 * 8);
        float4 b1 = *(const float4*)(bvec + l32 * 8 + 4);
        uint4  lm = *(const uint4*)(embb + (size_t)lt * DD + l32 * 8);
        const unsigned* lmd = (const unsigned*)&lm;
        const float* bb = (const float*)&b0;   // b0,b1 contiguous on stack? no —
        float bl[8] = {b0.x, b0.y, b0.z, b0.w, b1.x, b1.y, b1.z, b1.w};
        uint4 o;
        unsigned* od = (unsigned*)&o;
#pragma unroll
        for (int d = 0; d < 4; ++d) {
            float lo = bu2f((unsigned short)(lmd[d] & 0xffffu));
            float hi = __uint_as_float(lmd[d] & 0xffff0000u);
            float v0 = lo + (gate ? fmaxf(acc[2*d]   + bl[2*d],   0.f) : 0.f);
            float v1 = hi + (gate ? fmaxf(acc[2*d+1] + bl[2*d+1], 0.f) : 0.f);
            od[d] = (unsigned)f2bu(v0) | ((unsigned)f2bu(v1) << 16);
        }
        (void)bb;
        *(uint4*)(ftb + (size_t)w * DD + l32 * 8) = o;
    }
}

// ---------------------------------------------------------------------------
// Kernel 4: classifier GEMM. 64-row blocks, Wcfrag staged via straight
// 32KB copies (2 phases). Swapped operands -> float4 out stores.
// ---------------------------------------------------------------------------
__global__ __launch_bounds__(256, 4) void cls_mfma(
    const __hip_bfloat16* __restrict__ ftb,     // [M,256] bf16
    const __hip_bfloat16* __restrict__ Wcfrag,  // 64 groups x 512
    const float* __restrict__ bc,               // [104]
    float* __restrict__ out,                    // [M,104]
    int M)
{
    __shared__ __hip_bfloat16 lds[32 * 512];    // 32KB
    const int t    = threadIdx.x;
    const int lane = t & 63;
    const int w    = t >> 6;
    const int quad = lane >> 4;
    const int l16  = lane & 15;
    const int mw   = blockIdx.x * 64 + w * 16;

    int mrow = min(mw + l16, M - 1);
    bf16x8 ffrag[8];
    const __hip_bfloat16* arow = ftb + (size_t)mrow * DD + quad * 8;
#pragma unroll
    for (int k0 = 0; k0 < 8; ++k0)
        ffrag[k0] = *(const bf16x8*)(arow + k0 * 32);

    f32x4 acc[8];
#pragma unroll
    for (int nt = 0; nt < 8; ++nt) acc[nt] = (f32x4){0.f,0.f,0.f,0.f};

    for (int p = 0; p < 2; ++p) {
        if (p) __syncthreads();
#pragma unroll
        for (int it = 0; it < 8; ++it) {
            int idx = it * 256 + t;
            *(uint4*)(lds + (size_t)idx * 8) =
                *(const uint4*)(Wcfrag + (size_t)p * 16384 + (size_t)idx * 8);
        }
        __syncthreads();
#pragma unroll
        for (int kl = 0; kl < 4; ++kl) {
            int k0 = p * 4 + kl;
#pragma unroll
            for (int nt = 0; nt < 8; ++nt) {
                bf16x8 wf = *(const bf16x8*)(lds + (kl * 8 + nt) * 512 + lane * 8);
                acc[nt] = __builtin_amdgcn_mfma_f32_16x16x32_bf16(wf, ffrag[k0], acc[nt], 0, 0, 0);
            }
        }
    }

    int m = mw + l16;
    if (m < M) {
#pragma unroll
        for (int nt = 0; nt < 8; ++nt) {
            int c0 = nt * 16 + quad * 4;
            if (c0 <= 100) {
                float4 bia = *(const float4*)(bc + c0);
                float4 o;
                o.x = acc[nt][0] + bia.x;
                o.y = acc[nt][1] + bia.y;
                o.z = acc[nt][2] + bia.z;
                o.w = acc[nt][3] + bia.w;
                *(float4*)(out + (size_t)m * CC + c0) = o;
            }
        }
    }
}

// ---------------------------------------------------------------------------
extern "C" void kernel_launch(void* const* d_in, const int* in_sizes, int n_in,
                              void* d_out, int out_size, void* d_ws, size_t ws_size,
                              hipStream_t stream)
{
    const float* emb      = (const float*)d_in[0];
    const float* W        = (const float*)d_in[1];
    const float* bvec     = (const float*)d_in[2];
    const float* Wc       = (const float*)d_in[3];
    const float* bc       = (const float*)d_in[4];
    const int*   token_id = (const int*)d_in[5];
    const int*   src_idx  = (const int*)d_in[6];
    const int*   dst_idx  = (const int*)d_in[7];
    float*       out      = (float*)d_out;

    const int E     = in_sizes[6];
    const int Vemb  = in_sizes[0] / DD;
    const int n_dst = out_size / CC;
    (void)n_in; (void)ws_size;

    char* ws = (char*)d_ws;
    size_t off = 0;
    auto alloc = [&](size_t bytes) {
        void* p = ws + off;
        off = (off + bytes + 255) & ~(size_t)255;
        return p;
    };
    int* seg_start = (int*)alloc((size_t)n_dst * sizeof(int));
    int* seg_end   = (int*)alloc((size_t)n_dst * sizeof(int));
    int* edge_tok  = (int*)alloc((size_t)E * sizeof(int));
    __hip_bfloat16* embb   = (__hip_bfloat16*)alloc((size_t)Vemb * DD * 2);
    __hip_bfloat16* Webuf  = (__hip_bfloat16*)alloc((size_t)Vemb * DD * 2);
    __hip_bfloat16* ftb    = (__hip_bfloat16*)alloc((size_t)n_dst * DD * 2);
    __hip_bfloat16* Wfrag  = (__hip_bfloat16*)alloc((size_t)128 * 512 * 2);
    __hip_bfloat16* Wcfrag = (__hip_bfloat16*)alloc((size_t)64 * 512 * 2);

    const int PB = (E + 255) / 256;
    const int we_blocks  = (Vemb + 63) / 64;
    const int cls_blocks = (n_dst + 63) / 64;

    prep_all<<<PB + 48, 256, 0, stream>>>(
        token_id, src_idx, dst_idx, seg_start, seg_end, edge_tok, E, PB,
        W, Wc, Wfrag, Wcfrag);
    we_gemm<<<we_blocks, 256, 0, stream>>>(
        emb, Wfrag, Webuf, embb, Vemb);
    seg_rnn_kernel<<<(n_dst + 3) / 4, 256, 0, stream>>>(
        Webuf, embb, edge_tok, seg_start, seg_end, bvec, ftb, n_dst);
    cls_mfma<<<cls_blocks, 256, 0, stream>>>(
        ftb, Wcfrag, bc, out, n_dst);
}